// Round 8
// baseline (100.307 us; speedup 1.0000x reference)
//
#include <hip/hip_runtime.h>
#include <stdint.h>

constexpr int   kB  = 4;
constexpr int   kNS = 4096;
constexpr int   kVP = 2562;
constexpr int   kFP = 5120;
constexpr int   kVG = 6890;
constexpr int   kFG = 13776;
constexpr float kEPS  = 1e-12f;
constexpr int   kPB  = 256;   // partial-reduction blocks
constexpr int   kPREP_P = (kB * kFP + 255) / 256;   // 80
constexpr int   kPREP_G = (kB * kFG + 255) / 256;   // 216

// ---------------- Threefry-2x32 (exact JAX semantics) ----------------
__host__ __device__ inline void tf2x32(uint32_t k0, uint32_t k1,
                                       uint32_t& x0r, uint32_t& x1r) {
  uint32_t ks2 = k0 ^ k1 ^ 0x1BD11BDAu;
  uint32_t x0 = x0r + k0, x1 = x1r + k1;
#define TF_R(r) { x0 += x1; x1 = (x1 << (r)) | (x1 >> (32 - (r))); x1 ^= x0; }
  TF_R(13) TF_R(15) TF_R(26) TF_R(6)
  x0 += k1;  x1 += ks2 + 1u;
  TF_R(17) TF_R(29) TF_R(16) TF_R(24)
  x0 += ks2; x1 += k0 + 2u;
  TF_R(13) TF_R(15) TF_R(26) TF_R(6)
  x0 += k0;  x1 += k1 + 3u;
  TF_R(17) TF_R(29) TF_R(16) TF_R(24)
  x0 += k1;  x1 += ks2 + 4u;
  TF_R(13) TF_R(15) TF_R(26) TF_R(6)
  x0 += ks2; x1 += k0 + 5u;
#undef TF_R
  x0r = x0; x1r = x1;
}

__device__ inline float bits_to_unit(uint32_t b) {
  // JAX: bitcast((b>>9)|0x3f800000) - 1.0  ->  [0,1)
  return __uint_as_float((b >> 9) | 0x3f800000u) - 1.0f;
}

// faces may arrive as int32 (documented) or int64 (reference dtype). For
// int64 little-endian with values < 2^31, every odd 32-bit word is 0.
__device__ inline int faces_is64(const int* __restrict__ faces) {
  return (faces[1] == 0 && faces[3] == 0 && faces[5] == 0 && faces[7] == 0) ? 1 : 0;
}
__device__ inline int face_vtx(const int* __restrict__ faces, int f, int c,
                               int is64, int V) {
  int e = f * 3 + c;
  int v = faces[is64 ? (e << 1) : e];
  return v < 0 ? 0 : (v >= V ? V - 1 : v);
}

// ---------------- trivial diagnostic kernel ----------------
__global__ void mlk_write_scalar(float* out, float val) {
  if (threadIdx.x == 0 && blockIdx.x == 0) out[0] = val;
}

// ---------------- fused face geometry for BOTH meshes (+counter reset) -------
__global__ __launch_bounds__(256) void mlk_prep_faces2(
    const float* __restrict__ pverts, const int* __restrict__ pfaces,
    const float* __restrict__ gverts, const int* __restrict__ gfaces,
    float* __restrict__ wp, float* __restrict__ np,
    float* __restrict__ wg, float* __restrict__ ng,
    unsigned int* __restrict__ counter) {
  if (blockIdx.x == 0 && threadIdx.x == 0) *counter = 0u;  // for last-block loss
  int which = blockIdx.x >= kPREP_P;
  int blk   = which ? blockIdx.x - kPREP_P : blockIdx.x;
  const float* verts = which ? gverts : pverts;
  const int*   faces = which ? gfaces : pfaces;
  float* warea = which ? wg : wp;
  float* fnrm  = which ? ng : np;
  int V = which ? kVG : kVP;
  int F = which ? kFG : kFP;
  int idx = blk * 256 + threadIdx.x;
  if (idx >= kB * F) return;
  int is64 = faces_is64(faces);
  int b = idx / F, f = idx - b * F;
  int i0 = face_vtx(faces, f, 0, is64, V);
  int i1 = face_vtx(faces, f, 1, is64, V);
  int i2 = face_vtx(faces, f, 2, is64, V);
  const float* vb = verts + (size_t)b * V * 3;
  float ax = vb[i0*3+0], ay = vb[i0*3+1], az = vb[i0*3+2];
  float bx = vb[i1*3+0], by = vb[i1*3+1], bz = vb[i1*3+2];
  float cx = vb[i2*3+0], cy = vb[i2*3+1], cz = vb[i2*3+2];
  float e1x = bx-ax, e1y = by-ay, e1z = bz-az;
  float e2x = cx-ax, e2y = cy-ay, e2z = cz-az;
  float nx = e1y*e2z - e1z*e2y;
  float ny = e1z*e2x - e1x*e2z;
  float nz = e1x*e2y - e1y*e2x;
  float area2 = sqrtf(nx*nx + ny*ny + nz*nz);   // 2*area
  warea[idx] = 0.5f * area2 + kEPS;             // categorical weight
  float inv_n = 1.0f / (area2 + kEPS);
  fnrm[3*idx+0] = nx*inv_n;
  fnrm[3*idx+1] = ny*inv_n;
  fnrm[3*idx+2] = nz*inv_n;
}

// ---------------- fused in-place prefix sums (8 blocks: 4 pred + 4 gt) --------
__global__ __launch_bounds__(256) void mlk_prefix2(
    float* __restrict__ wp, float* __restrict__ wg) {
  int which = blockIdx.x >> 2;
  int b = blockIdx.x & 3, tid = threadIdx.x;
  int F = which ? kFG : kFP;
  float* wb = (which ? wg : wp) + (size_t)b * F;
  int C = (F + 255) / 256;
  int lo = tid * C;
  int hi = lo + C; if (hi > F) hi = F; if (lo > F) lo = F;
  float s = 0.f;
  for (int i = lo; i < hi; ++i) s += wb[i];
  __shared__ float ps[256];
  ps[tid] = s;
  __syncthreads();
  for (int off = 1; off < 256; off <<= 1) {
    float v = (tid >= off) ? ps[tid - off] : 0.f;
    __syncthreads();
    ps[tid] += v;
    __syncthreads();
  }
  float p = ps[tid] - s;            // exclusive offset for this chunk
  for (int i = lo; i < hi; ++i) { p += wb[i]; wb[i] = p; }
}

// ---------------- fused categorical (inverse-CDF) + barycentric gen ----------
// grid 256 x 64 thr: global g = 0..16383; which = g>>13; t = g&8191.
// The two halves' binary searches are interleaved for 2-deep MLP.
__global__ __launch_bounds__(64) void mlk_sample_gen(
    const float* __restrict__ pverts, const int* __restrict__ pfaces,
    const float* __restrict__ pref_p, const float* __restrict__ fnrm_p,
    float* __restrict__ pred_pts, float* __restrict__ pred_nrm,
    const float* __restrict__ gverts, const int* __restrict__ gfaces,
    const float* __restrict__ pref_g, const float* __restrict__ fnrm_g,
    float* __restrict__ gt_pts, float* __restrict__ gt_nrm,
    uint32_t pf0, uint32_t pf1, uint32_t pu0, uint32_t pu1, uint32_t pv0, uint32_t pv1,
    uint32_t gf0, uint32_t gf1, uint32_t gu0, uint32_t gu1, uint32_t gv0, uint32_t gv1) {
  int g = blockIdx.x * 64 + threadIdx.x;
  int which = g >> 13;
  int t = g & 8191;
  const float* verts = which ? gverts : pverts;
  const int*   faces = which ? gfaces : pfaces;
  const float* pref  = which ? pref_g : pref_p;
  const float* fnrm  = which ? fnrm_g : fnrm_p;
  float* pts  = which ? gt_pts : pred_pts;
  float* pnrm = which ? gt_nrm : pred_nrm;
  int V = which ? kVG : kVP;
  int F = which ? kFG : kFP;
  uint32_t kf0 = which ? gf0 : pf0, kf1 = which ? gf1 : pf1;
  uint32_t ku0 = which ? gu0 : pu0, ku1 = which ? gu1 : pu1;
  uint32_t kv0 = which ? gv0 : pv0, kv1 = which ? gv1 : pv1;
  int is64 = faces_is64(faces);

  uint32_t fx0 = (uint32_t)t, fx1 = (uint32_t)(t + 8192);
  tf2x32(kf0, kf1, fx0, fx1);
  uint32_t ux0 = (uint32_t)t, ux1 = (uint32_t)(t + 8192);
  tf2x32(ku0, ku1, ux0, ux1);
  uint32_t vx0 = (uint32_t)t, vx1 = (uint32_t)(t + 8192);
  tf2x32(kv0, kv1, vx0, vx1);

  // --- interleaved inverse-CDF searches for rows t and t+8192 ---
  int b0 = t >> 12, b1 = b0 + 2;
  const float* P0 = pref + (size_t)b0 * F;
  const float* P1 = pref + (size_t)b1 * F;
  float tg0 = bits_to_unit(fx0) * P0[F - 1];
  float tg1 = bits_to_unit(fx1) * P1[F - 1];
  int lo0 = 0, hi0 = F - 1, lo1 = 0, hi1 = F - 1;
  while (lo0 < hi0 || lo1 < hi1) {
    if (lo0 < hi0) {
      int mid = (lo0 + hi0) >> 1;
      if (P0[mid] > tg0) hi0 = mid; else lo0 = mid + 1;
    }
    if (lo1 < hi1) {
      int mid = (lo1 + hi1) >> 1;
      if (P1[mid] > tg1) hi1 = mid; else lo1 = mid + 1;
    }
  }
  int fid0 = lo0, fid1 = lo1;

#pragma unroll
  for (int half = 0; half < 2; ++half) {
    int i = t + half * 8192;                    // flat (b*kNS+s)
    int b = i >> 12;
    int fid = half ? fid1 : fid0;
    float u = bits_to_unit(half ? ux1 : ux0);
    float v = bits_to_unit(half ? vx1 : vx0);
    const float* vb = verts + (size_t)b * V * 3;
    int i0 = face_vtx(faces, fid, 0, is64, V);
    int i1 = face_vtx(faces, fid, 1, is64, V);
    int i2 = face_vtx(faces, fid, 2, is64, V);
    float r1 = sqrtf(u);
    float w0 = 1.0f - r1, w1 = r1 * (1.0f - v), w2 = r1 * v;
#pragma unroll
    for (int c = 0; c < 3; ++c) {
      pts[i*3+c] = w0 * vb[i0*3+c] + w1 * vb[i1*3+c] + w2 * vb[i2*3+c];
      pnrm[i*3+c] = fnrm[((size_t)b*F + fid)*3 + c];
    }
  }
}

// ---------------- chamfer v3: 2 queries/lane, 8 waves x 512 refs -------------
// grid 256: dir(2) x batch(4) x qchunk(32). Block = 512 thr = 8 waves.
// All 8 waves share the same 128 queries (2/lane); wave w scans refs
// [512w, 512w+512) as 128 float4 groups. Each ds_read_b128 serves 2 queries
// (halved LDS issue vs 1 query/lane). Min chains split A{0,1}/B{2,3};
// all merges tie-break to the smaller ref index (first-index semantics).
__global__ __launch_bounds__(512) void mlk_chamfer3(
    const float* __restrict__ pred_pts, const float* __restrict__ gt_pts,
    float* __restrict__ min_p2g, float* __restrict__ min_g2p,
    int* __restrict__ idx_p2g) {
  int bid = blockIdx.x;
  int dir = bid >> 7;            // 0: pred->gt (needs idx), 1: gt->pred
  int r   = bid & 127;
  int b   = r >> 5;
  int qc  = r & 31;
  const float* qpts = dir ? gt_pts   : pred_pts;
  const float* rpts = dir ? pred_pts : gt_pts;
  int wave = threadIdx.x >> 6;
  int lane = threadIdx.x & 63;

  __shared__ float4 lpx4[kNS/4], lpy4[kNS/4], lpz4[kNS/4];  // 48 KB SoA
  float* lpx = (float*)lpx4; float* lpy = (float*)lpy4; float* lpz = (float*)lpz4;
  const float* rb = rpts + (size_t)b * kNS * 3;
  for (int i = threadIdx.x; i < kNS; i += 512) {
    lpx[i] = rb[3*i+0];
    lpy[i] = rb[3*i+1];
    lpz[i] = rb[3*i+2];
  }
  __syncthreads();

  int q0 = qc * 128 + lane;           // query pair: q0 and q0+64
  int gq0 = b * kNS + q0;
  int gq1 = gq0 + 64;
  float px0 = qpts[gq0*3+0], py0 = qpts[gq0*3+1], pz0 = qpts[gq0*3+2];
  float px1 = qpts[gq1*3+0], py1 = qpts[gq1*3+1], pz1 = qpts[gq1*3+2];
  int j0 = wave * 128;
  float best0, best1; int bidx0 = 0, bidx1 = 0;

  if (dir == 0) {
    float bA0 = INFINITY, bB0 = INFINITY, bA1 = INFINITY, bB1 = INFINITY;
    int iA0 = 0, iB0 = 0, iA1 = 0, iB1 = 0;
#pragma unroll 2
    for (int j = j0; j < j0 + 128; ++j) {
      float4 X = lpx4[j], Y = lpy4[j], Z = lpz4[j];
      int m = j << 2;
      float dx, dy, dz, d;
      dx = px0-X.x; dy = py0-Y.x; dz = pz0-Z.x; d = dx*dx+dy*dy+dz*dz; if (d < bA0) { bA0 = d; iA0 = m; }
      dx = px0-X.y; dy = py0-Y.y; dz = pz0-Z.y; d = dx*dx+dy*dy+dz*dz; if (d < bA0) { bA0 = d; iA0 = m|1; }
      dx = px0-X.z; dy = py0-Y.z; dz = pz0-Z.z; d = dx*dx+dy*dy+dz*dz; if (d < bB0) { bB0 = d; iB0 = m|2; }
      dx = px0-X.w; dy = py0-Y.w; dz = pz0-Z.w; d = dx*dx+dy*dy+dz*dz; if (d < bB0) { bB0 = d; iB0 = m|3; }
      dx = px1-X.x; dy = py1-Y.x; dz = pz1-Z.x; d = dx*dx+dy*dy+dz*dz; if (d < bA1) { bA1 = d; iA1 = m; }
      dx = px1-X.y; dy = py1-Y.y; dz = pz1-Z.y; d = dx*dx+dy*dy+dz*dz; if (d < bA1) { bA1 = d; iA1 = m|1; }
      dx = px1-X.z; dy = py1-Y.z; dz = pz1-Z.z; d = dx*dx+dy*dy+dz*dz; if (d < bB1) { bB1 = d; iB1 = m|2; }
      dx = px1-X.w; dy = py1-Y.w; dz = pz1-Z.w; d = dx*dx+dy*dy+dz*dz; if (d < bB1) { bB1 = d; iB1 = m|3; }
    }
    if (bB0 < bA0 || (bB0 == bA0 && iB0 < iA0)) { best0 = bB0; bidx0 = iB0; } else { best0 = bA0; bidx0 = iA0; }
    if (bB1 < bA1 || (bB1 == bA1 && iB1 < iA1)) { best1 = bB1; bidx1 = iB1; } else { best1 = bA1; bidx1 = iA1; }
  } else {
    float bA0 = INFINITY, bB0 = INFINITY, bA1 = INFINITY, bB1 = INFINITY;
#pragma unroll 2
    for (int j = j0; j < j0 + 128; ++j) {
      float4 X = lpx4[j], Y = lpy4[j], Z = lpz4[j];
      float dx, dy, dz;
      dx = px0-X.x; dy = py0-Y.x; dz = pz0-Z.x; float d0 = dx*dx+dy*dy+dz*dz;
      dx = px0-X.y; dy = py0-Y.y; dz = pz0-Z.y; float d1 = dx*dx+dy*dy+dz*dz;
      dx = px0-X.z; dy = py0-Y.z; dz = pz0-Z.z; float d2 = dx*dx+dy*dy+dz*dz;
      dx = px0-X.w; dy = py0-Y.w; dz = pz0-Z.w; float d3 = dx*dx+dy*dy+dz*dz;
      bA0 = fminf(bA0, fminf(d0, d1));
      bB0 = fminf(bB0, fminf(d2, d3));
      dx = px1-X.x; dy = py1-Y.x; dz = pz1-Z.x; d0 = dx*dx+dy*dy+dz*dz;
      dx = px1-X.y; dy = py1-Y.y; dz = pz1-Z.y; d1 = dx*dx+dy*dy+dz*dz;
      dx = px1-X.z; dy = py1-Y.z; dz = pz1-Z.z; d2 = dx*dx+dy*dy+dz*dz;
      dx = px1-X.w; dy = py1-Y.w; dz = pz1-Z.w; d3 = dx*dx+dy*dy+dz*dz;
      bA1 = fminf(bA1, fminf(d0, d1));
      bB1 = fminf(bB1, fminf(d2, d3));
    }
    best0 = fminf(bA0, bB0);
    best1 = fminf(bA1, bB1);
  }

  __shared__ float cv[8][128];
  __shared__ int   ci[8][128];
  cv[wave][lane]      = best0; ci[wave][lane]      = bidx0;
  cv[wave][lane + 64] = best1; ci[wave][lane + 64] = bidx1;
  __syncthreads();
  if (threadIdx.x < 128) {
    int ql = threadIdx.x;
    float bv = cv[0][ql]; int bi = ci[0][ql];
#pragma unroll
    for (int wv = 1; wv < 8; ++wv) {
      float v = cv[wv][ql];
      int   i = ci[wv][ql];
      if (v < bv || (v == bv && i < bi)) { bv = v; bi = i; }
    }
    int gi = b * kNS + qc * 128 + ql;
    if (dir == 0) { min_p2g[gi] = bv; idx_p2g[gi] = bi; }
    else          { min_g2p[gi] = bv; }
  }
}

// ---------------- fused loss reduction (last-block combine) ----------------
__global__ __launch_bounds__(256) void mlk_loss(
    const float* __restrict__ min_p2g, const float* __restrict__ min_g2p,
    const float* __restrict__ pred_nrm, const float* __restrict__ gt_nrm,
    const int* __restrict__ idx_p2g,
    const float* __restrict__ pverts, const int* __restrict__ pfaces,
    float* __restrict__ partial, unsigned int* __restrict__ counter,
    float* __restrict__ out) {
  int tid = threadIdx.x;
  int gidx = blockIdx.x * 256 + tid;
  const int stride = kPB * 256;
  int is64 = faces_is64(pfaces);
  float s1 = 0.f, s2 = 0.f, sc = 0.f, se = 0.f;
  for (int i = gidx; i < kB * kNS; i += stride) {
    s1 += min_p2g[i];
    s2 += min_g2p[i];
    int b = i >> 12;
    int m = idx_p2g[i];
    m = m < 0 ? 0 : (m >= kNS ? kNS - 1 : m);
    const float* pn = pred_nrm + (size_t)i * 3;
    const float* gn = gt_nrm + ((size_t)b * kNS + m) * 3;
    sc += fabsf(pn[0]*gn[0] + pn[1]*gn[1] + pn[2]*gn[2]);
  }
  for (int e = gidx; e < kB * kFP * 3; e += stride) {
    int b = e / (kFP * 3);
    int r = e - b * kFP * 3;
    int f = r / 3, k = r - f * 3;
    int ia, ib;
    if (k == 0)      { ia = face_vtx(pfaces, f, 0, is64, kVP); ib = face_vtx(pfaces, f, 1, is64, kVP); }
    else if (k == 1) { ia = face_vtx(pfaces, f, 1, is64, kVP); ib = face_vtx(pfaces, f, 2, is64, kVP); }
    else             { ia = face_vtx(pfaces, f, 2, is64, kVP); ib = face_vtx(pfaces, f, 0, is64, kVP); }
    const float* vb = pverts + (size_t)b * kVP * 3;
    float dx = vb[ib*3+0] - vb[ia*3+0];
    float dy = vb[ib*3+1] - vb[ia*3+1];
    float dz = vb[ib*3+2] - vb[ia*3+2];
    se += dx*dx + dy*dy + dz*dz;
  }
  __shared__ float r1a[256], r2a[256], r3a[256], r4a[256];
  r1a[tid] = s1; r2a[tid] = s2; r3a[tid] = sc; r4a[tid] = se;
  __syncthreads();
  for (int off = 128; off > 0; off >>= 1) {
    if (tid < off) {
      r1a[tid] += r1a[tid+off];
      r2a[tid] += r2a[tid+off];
      r3a[tid] += r3a[tid+off];
      r4a[tid] += r4a[tid+off];
    }
    __syncthreads();
  }
  if (tid == 0) {
    partial[blockIdx.x*4+0] = r1a[0];
    partial[blockIdx.x*4+1] = r2a[0];
    partial[blockIdx.x*4+2] = r3a[0];
    partial[blockIdx.x*4+3] = r4a[0];
  }
  // --- last block combines (rocPRIM-style ticket; deterministic sums) ---
  __threadfence();
  __shared__ unsigned int ticket;
  if (tid == 0) ticket = atomicAdd(counter, 1u);
  __syncthreads();
  if (ticket == kPB - 1) {
    __threadfence();
    volatile const float* vp = partial;
    r1a[tid] = vp[tid*4+0];
    r2a[tid] = vp[tid*4+1];
    r3a[tid] = vp[tid*4+2];
    r4a[tid] = vp[tid*4+3];
    __syncthreads();
    for (int off = 128; off > 0; off >>= 1) {
      if (tid < off) {
        r1a[tid] += r1a[tid+off];
        r2a[tid] += r2a[tid+off];
        r3a[tid] += r3a[tid+off];
        r4a[tid] += r4a[tid+off];
      }
      __syncthreads();
    }
    if (tid == 0) {
      const float invN = 1.0f / (float)(kB * kNS);
      float chamfer = r1a[0] * invN + r2a[0] * invN;
      float nloss = 1.0f - r3a[0] * invN;
      float eloss = r4a[0] / (float)(kB * kFP * 3);
      out[0] = 1.0f * chamfer + 0.1f * nloss + 0.5f * eloss;
    }
  }
}

// ---------------- host side ----------------
extern "C" void kernel_launch(void* const* d_in, const int* in_sizes, int n_in,
                              void* d_out, int out_size, void* d_ws, size_t ws_size,
                              hipStream_t stream) {
  const float* pverts = (const float*)d_in[0];
  const int*   pfaces = (const int*)d_in[1];
  const float* gverts = (const float*)d_in[2];
  const int*   gfaces = (const int*)d_in[3];
  float* out = (float*)d_out;

  const size_t needF =
      (size_t)kB*kFP + (size_t)kB*kFG +          // weights -> prefix (in-place)
      (size_t)kB*kFP*3 + (size_t)kB*kFG*3 +
      4*(size_t)kB*kNS*3 +
      2*(size_t)kB*kNS +
      (size_t)kPB*4 + 1 +                        // partials + ticket counter
      (size_t)kB*kNS;                            // idx_p2g
  if (ws_size < needF * 4) {
    mlk_write_scalar<<<1, 64, 0, stream>>>(out, -1.0f);
    return;
  }

  // --- JAX threefry key chain (host, pure arithmetic) ---
  uint32_t a0 = 0u, a1 = 2u; tf2x32(0u, 42u, a0, a1);
  uint32_t b0 = 1u, b1 = 3u; tf2x32(0u, 42u, b0, b1);
  uint32_t kp0 = a0, kp1 = b0;
  uint32_t kg0 = a1, kg1 = b1;
  uint32_t kpred[6], kgt[6];
  {
    uint32_t p0 = 0u, p1 = 3u; tf2x32(kp0, kp1, p0, p1);
    uint32_t q0 = 1u, q1 = 4u; tf2x32(kp0, kp1, q0, q1);
    uint32_t r0 = 2u, r1 = 5u; tf2x32(kp0, kp1, r0, r1);
    kpred[0]=p0; kpred[1]=q0; kpred[2]=r0; kpred[3]=p1; kpred[4]=q1; kpred[5]=r1;
  }
  {
    uint32_t p0 = 0u, p1 = 3u; tf2x32(kg0, kg1, p0, p1);
    uint32_t q0 = 1u, q1 = 4u; tf2x32(kg0, kg1, q0, q1);
    uint32_t r0 = 2u, r1 = 5u; tf2x32(kg0, kg1, r0, r1);
    kgt[0]=p0; kgt[1]=q0; kgt[2]=r0; kgt[3]=p1; kgt[4]=q1; kgt[5]=r1;
  }

  // --- workspace carve (all 4-byte elements) ---
  float* ws = (float*)d_ws;
  float* pref_p   = ws; ws += kB * kFP;          // weights, then in-place prefix
  float* pref_g   = ws; ws += kB * kFG;
  float* fnrm_p   = ws; ws += kB * kFP * 3;
  float* fnrm_g   = ws; ws += kB * kFG * 3;
  float* pred_pts = ws; ws += kB * kNS * 3;
  float* gt_pts   = ws; ws += kB * kNS * 3;
  float* pred_nrm = ws; ws += kB * kNS * 3;
  float* gt_nrm   = ws; ws += kB * kNS * 3;
  float* min_p2g  = ws; ws += kB * kNS;
  float* min_g2p  = ws; ws += kB * kNS;
  float* partial  = ws; ws += kPB * 4;
  unsigned int* counter = (unsigned int*)ws; ws += 1;
  int* idx_p2g = (int*)ws; ws += kB * kNS;

  mlk_prep_faces2<<<kPREP_P + kPREP_G, 256, 0, stream>>>(
      pverts, pfaces, gverts, gfaces, pref_p, fnrm_p, pref_g, fnrm_g, counter);

  mlk_prefix2<<<8, 256, 0, stream>>>(pref_p, pref_g);

  mlk_sample_gen<<<256, 64, 0, stream>>>(
      pverts, pfaces, pref_p, fnrm_p, pred_pts, pred_nrm,
      gverts, gfaces, pref_g, fnrm_g, gt_pts, gt_nrm,
      kpred[0], kpred[1], kpred[2], kpred[3], kpred[4], kpred[5],
      kgt[0],  kgt[1],  kgt[2],  kgt[3],  kgt[4],  kgt[5]);

  mlk_chamfer3<<<256, 512, 0, stream>>>(pred_pts, gt_pts, min_p2g, min_g2p, idx_p2g);

  mlk_loss<<<kPB, 256, 0, stream>>>(min_p2g, min_g2p, pred_nrm, gt_nrm, idx_p2g,
                                    pverts, pfaces, partial, counter, out);
}

// Round 9
// 84.871 us; speedup vs baseline: 1.1819x; 1.1819x over previous
//
#include <hip/hip_runtime.h>
#include <stdint.h>

constexpr int   kB  = 4;
constexpr int   kNS = 4096;
constexpr int   kVP = 2562;
constexpr int   kFP = 5120;
constexpr int   kVG = 6890;
constexpr int   kFG = 13776;
constexpr float kEPS  = 1e-12f;
constexpr int   kPB  = 256;   // partial-reduction blocks
constexpr int   kPREP_P = (kB * kFP + 255) / 256;   // 80
constexpr int   kPREP_G = (kB * kFG + 255) / 256;   // 216

// ---------------- Threefry-2x32 (exact JAX semantics) ----------------
__host__ __device__ inline void tf2x32(uint32_t k0, uint32_t k1,
                                       uint32_t& x0r, uint32_t& x1r) {
  uint32_t ks2 = k0 ^ k1 ^ 0x1BD11BDAu;
  uint32_t x0 = x0r + k0, x1 = x1r + k1;
#define TF_R(r) { x0 += x1; x1 = (x1 << (r)) | (x1 >> (32 - (r))); x1 ^= x0; }
  TF_R(13) TF_R(15) TF_R(26) TF_R(6)
  x0 += k1;  x1 += ks2 + 1u;
  TF_R(17) TF_R(29) TF_R(16) TF_R(24)
  x0 += ks2; x1 += k0 + 2u;
  TF_R(13) TF_R(15) TF_R(26) TF_R(6)
  x0 += k0;  x1 += k1 + 3u;
  TF_R(17) TF_R(29) TF_R(16) TF_R(24)
  x0 += k1;  x1 += ks2 + 4u;
  TF_R(13) TF_R(15) TF_R(26) TF_R(6)
  x0 += ks2; x1 += k0 + 5u;
#undef TF_R
  x0r = x0; x1r = x1;
}

__device__ inline float bits_to_unit(uint32_t b) {
  // JAX: bitcast((b>>9)|0x3f800000) - 1.0  ->  [0,1)
  return __uint_as_float((b >> 9) | 0x3f800000u) - 1.0f;
}

// faces may arrive as int32 (documented) or int64 (reference dtype). For
// int64 little-endian with values < 2^31, every odd 32-bit word is 0.
__device__ inline int faces_is64(const int* __restrict__ faces) {
  return (faces[1] == 0 && faces[3] == 0 && faces[5] == 0 && faces[7] == 0) ? 1 : 0;
}
__device__ inline int face_vtx(const int* __restrict__ faces, int f, int c,
                               int is64, int V) {
  int e = f * 3 + c;
  int v = faces[is64 ? (e << 1) : e];
  return v < 0 ? 0 : (v >= V ? V - 1 : v);
}

// ---------------- trivial diagnostic kernel ----------------
__global__ void mlk_write_scalar(float* out, float val) {
  if (threadIdx.x == 0 && blockIdx.x == 0) out[0] = val;
}

// ---------------- fused face geometry for BOTH meshes ----------------
__global__ __launch_bounds__(256) void mlk_prep_faces2(
    const float* __restrict__ pverts, const int* __restrict__ pfaces,
    const float* __restrict__ gverts, const int* __restrict__ gfaces,
    float* __restrict__ wp, float* __restrict__ np,
    float* __restrict__ wg, float* __restrict__ ng) {
  int which = blockIdx.x >= kPREP_P;
  int blk   = which ? blockIdx.x - kPREP_P : blockIdx.x;
  const float* verts = which ? gverts : pverts;
  const int*   faces = which ? gfaces : pfaces;
  float* warea = which ? wg : wp;
  float* fnrm  = which ? ng : np;
  int V = which ? kVG : kVP;
  int F = which ? kFG : kFP;
  int idx = blk * 256 + threadIdx.x;
  if (idx >= kB * F) return;
  int is64 = faces_is64(faces);
  int b = idx / F, f = idx - b * F;
  int i0 = face_vtx(faces, f, 0, is64, V);
  int i1 = face_vtx(faces, f, 1, is64, V);
  int i2 = face_vtx(faces, f, 2, is64, V);
  const float* vb = verts + (size_t)b * V * 3;
  float ax = vb[i0*3+0], ay = vb[i0*3+1], az = vb[i0*3+2];
  float bx = vb[i1*3+0], by = vb[i1*3+1], bz = vb[i1*3+2];
  float cx = vb[i2*3+0], cy = vb[i2*3+1], cz = vb[i2*3+2];
  float e1x = bx-ax, e1y = by-ay, e1z = bz-az;
  float e2x = cx-ax, e2y = cy-ay, e2z = cz-az;
  float nx = e1y*e2z - e1z*e2y;
  float ny = e1z*e2x - e1x*e2z;
  float nz = e1x*e2y - e1y*e2x;
  float area2 = sqrtf(nx*nx + ny*ny + nz*nz);   // 2*area
  warea[idx] = 0.5f * area2 + kEPS;             // categorical weight
  float inv_n = 1.0f / (area2 + kEPS);
  fnrm[3*idx+0] = nx*inv_n;
  fnrm[3*idx+1] = ny*inv_n;
  fnrm[3*idx+2] = nz*inv_n;
}

// ---------------- fused in-place prefix sums (8 blocks: 4 pred + 4 gt) --------
__global__ __launch_bounds__(256) void mlk_prefix2(
    float* __restrict__ wp, float* __restrict__ wg) {
  int which = blockIdx.x >> 2;
  int b = blockIdx.x & 3, tid = threadIdx.x;
  int F = which ? kFG : kFP;
  float* wb = (which ? wg : wp) + (size_t)b * F;
  int C = (F + 255) / 256;
  int lo = tid * C;
  int hi = lo + C; if (hi > F) hi = F; if (lo > F) lo = F;
  float s = 0.f;
  for (int i = lo; i < hi; ++i) s += wb[i];
  __shared__ float ps[256];
  ps[tid] = s;
  __syncthreads();
  for (int off = 1; off < 256; off <<= 1) {
    float v = (tid >= off) ? ps[tid - off] : 0.f;
    __syncthreads();
    ps[tid] += v;
    __syncthreads();
  }
  float p = ps[tid] - s;            // exclusive offset for this chunk
  for (int i = lo; i < hi; ++i) { p += wb[i]; wb[i] = p; }
}

// ---------------- fused categorical (inverse-CDF) + barycentric gen ----------
// grid 64: blocks 0..31 pred, 32..63 gt. Thread t handles rows t and t+8192.
__global__ __launch_bounds__(256) void mlk_sample_gen(
    const float* __restrict__ pverts, const int* __restrict__ pfaces,
    const float* __restrict__ pref_p, const float* __restrict__ fnrm_p,
    float* __restrict__ pred_pts, float* __restrict__ pred_nrm,
    const float* __restrict__ gverts, const int* __restrict__ gfaces,
    const float* __restrict__ pref_g, const float* __restrict__ fnrm_g,
    float* __restrict__ gt_pts, float* __restrict__ gt_nrm,
    uint32_t pf0, uint32_t pf1, uint32_t pu0, uint32_t pu1, uint32_t pv0, uint32_t pv1,
    uint32_t gf0, uint32_t gf1, uint32_t gu0, uint32_t gu1, uint32_t gv0, uint32_t gv1) {
  int which = blockIdx.x >> 5;
  int t = ((blockIdx.x & 31) << 8) + threadIdx.x;   // 0..8191
  const float* verts = which ? gverts : pverts;
  const int*   faces = which ? gfaces : pfaces;
  const float* pref  = which ? pref_g : pref_p;
  const float* fnrm  = which ? fnrm_g : fnrm_p;
  float* pts  = which ? gt_pts : pred_pts;
  float* pnrm = which ? gt_nrm : pred_nrm;
  int V = which ? kVG : kVP;
  int F = which ? kFG : kFP;
  uint32_t kf0 = which ? gf0 : pf0, kf1 = which ? gf1 : pf1;
  uint32_t ku0 = which ? gu0 : pu0, ku1 = which ? gu1 : pu1;
  uint32_t kv0 = which ? gv0 : pv0, kv1 = which ? gv1 : pv1;
  int is64 = faces_is64(faces);

  uint32_t fx0 = (uint32_t)t, fx1 = (uint32_t)(t + 8192);
  tf2x32(kf0, kf1, fx0, fx1);
  uint32_t ux0 = (uint32_t)t, ux1 = (uint32_t)(t + 8192);
  tf2x32(ku0, ku1, ux0, ux1);
  uint32_t vx0 = (uint32_t)t, vx1 = (uint32_t)(t + 8192);
  tf2x32(kv0, kv1, vx0, vx1);

#pragma unroll
  for (int half = 0; half < 2; ++half) {
    int i = t + half * 8192;                    // flat (b*kNS+s)
    int b = i >> 12;
    // --- inverse-CDF face draw ---
    float uf = bits_to_unit(half ? fx1 : fx0);
    const float* Pb = pref + (size_t)b * F;
    float target = uf * Pb[F - 1];
    int lo = 0, hi = F - 1;
    while (lo < hi) {                           // first f with P_incl[f] > target
      int mid = (lo + hi) >> 1;
      if (Pb[mid] > target) hi = mid; else lo = mid + 1;
    }
    int fid = lo;
    // --- barycentric point ---
    float u = bits_to_unit(half ? ux1 : ux0);
    float v = bits_to_unit(half ? vx1 : vx0);
    const float* vb = verts + (size_t)b * V * 3;
    int i0 = face_vtx(faces, fid, 0, is64, V);
    int i1 = face_vtx(faces, fid, 1, is64, V);
    int i2 = face_vtx(faces, fid, 2, is64, V);
    float r1 = sqrtf(u);
    float w0 = 1.0f - r1, w1 = r1 * (1.0f - v), w2 = r1 * v;
#pragma unroll
    for (int c = 0; c < 3; ++c) {
      pts[i*3+c] = w0 * vb[i0*3+c] + w1 * vb[i1*3+c] + w2 * vb[i2*3+c];
      pnrm[i*3+c] = fnrm[((size_t)b*F + fid)*3 + c];
    }
  }
}

// ---------------- chamfer v4: 8 waves x 512 refs, 1 query/lane ---------------
// grid = 512: dir(2) x batch(4) x qchunk(64). Block = 512 thr = 8 waves.
// All waves share the block's 64 queries (lane = query); wave w scans refs
// [512w, 512w+512) as 128 float4 groups. SoA LDS broadcast reads; min chains
// split A{0,1}/B{2,3}; all merges tie-break to the smaller ref index.
// LDS = 48K (SoA) + 4K (merge) = 53 KB -> 3 blocks/CU capacity; grid 512 = 2
// resident/CU -> 16 waves/CU (4/SIMD) latency hiding.
__global__ __launch_bounds__(512) void mlk_chamfer4(
    const float* __restrict__ pred_pts, const float* __restrict__ gt_pts,
    float* __restrict__ min_p2g, float* __restrict__ min_g2p,
    int* __restrict__ idx_p2g) {
  int bid = blockIdx.x;
  int dir = bid >> 8;            // 0: pred->gt (needs idx), 1: gt->pred
  int r   = bid & 255;
  int b   = r >> 6;
  int qc  = r & 63;
  const float* qpts = dir ? gt_pts   : pred_pts;
  const float* rpts = dir ? pred_pts : gt_pts;
  int wave = threadIdx.x >> 6;
  int lane = threadIdx.x & 63;

  __shared__ float4 lpx4[kNS/4], lpy4[kNS/4], lpz4[kNS/4];  // 48 KB SoA
  float* lpx = (float*)lpx4; float* lpy = (float*)lpy4; float* lpz = (float*)lpz4;
  const float* rb = rpts + (size_t)b * kNS * 3;
  for (int i = threadIdx.x; i < kNS; i += 512) {
    lpx[i] = rb[3*i+0];
    lpy[i] = rb[3*i+1];
    lpz[i] = rb[3*i+2];
  }
  __syncthreads();

  int q  = qc * 64 + lane;
  int gi = b * kNS + q;
  float px = qpts[gi*3+0], py = qpts[gi*3+1], pz = qpts[gi*3+2];
  int j0 = wave * 128;               // 128 float4 groups = 512 refs per wave
  float best; int bidx = 0;

  if (dir == 0) {
    float bA = INFINITY, bB = INFINITY; int iA = 0, iB = 0;
#pragma unroll 2
    for (int j = j0; j < j0 + 128; ++j) {
      float4 X = lpx4[j], Y = lpy4[j], Z = lpz4[j];
      int m = j << 2;
      float dx, dy, dz;
      dx = px-X.x; dy = py-Y.x; dz = pz-Z.x; float d0 = dx*dx+dy*dy+dz*dz;
      dx = px-X.y; dy = py-Y.y; dz = pz-Z.y; float d1 = dx*dx+dy*dy+dz*dz;
      dx = px-X.z; dy = py-Y.z; dz = pz-Z.z; float d2 = dx*dx+dy*dy+dz*dz;
      dx = px-X.w; dy = py-Y.w; dz = pz-Z.w; float d3 = dx*dx+dy*dy+dz*dz;
      if (d0 < bA) { bA = d0; iA = m; }
      if (d1 < bA) { bA = d1; iA = m | 1; }
      if (d2 < bB) { bB = d2; iB = m | 2; }
      if (d3 < bB) { bB = d3; iB = m | 3; }
    }
    if (bB < bA || (bB == bA && iB < iA)) { best = bB; bidx = iB; }
    else                                  { best = bA; bidx = iA; }
  } else {
    float bA = INFINITY, bB = INFINITY;
#pragma unroll 2
    for (int j = j0; j < j0 + 128; ++j) {
      float4 X = lpx4[j], Y = lpy4[j], Z = lpz4[j];
      float dx, dy, dz;
      dx = px-X.x; dy = py-Y.x; dz = pz-Z.x; float d0 = dx*dx+dy*dy+dz*dz;
      dx = px-X.y; dy = py-Y.y; dz = pz-Z.y; float d1 = dx*dx+dy*dy+dz*dz;
      dx = px-X.z; dy = py-Y.z; dz = pz-Z.z; float d2 = dx*dx+dy*dy+dz*dz;
      dx = px-X.w; dy = py-Y.w; dz = pz-Z.w; float d3 = dx*dx+dy*dy+dz*dz;
      bA = fminf(bA, fminf(d0, d1));
      bB = fminf(bB, fminf(d2, d3));
    }
    best = fminf(bA, bB);
  }

  __shared__ float cv[8][64];
  __shared__ int   ci[8][64];
  cv[wave][lane] = best; ci[wave][lane] = bidx;
  __syncthreads();
  if (threadIdx.x < 64) {
    float bv = cv[0][lane]; int bi = ci[0][lane];
#pragma unroll
    for (int wv = 1; wv < 8; ++wv) {
      float v = cv[wv][lane];
      int   i = ci[wv][lane];
      if (v < bv || (v == bv && i < bi)) { bv = v; bi = i; }
    }
    if (dir == 0) { min_p2g[gi] = bv; idx_p2g[gi] = bi; }
    else          { min_g2p[gi] = bv; }
  }
}

// ---------------- loss reduction stage 1: grid-wide partials ----------------
__global__ __launch_bounds__(256) void mlk_loss_partial(
    const float* __restrict__ min_p2g, const float* __restrict__ min_g2p,
    const float* __restrict__ pred_nrm, const float* __restrict__ gt_nrm,
    const int* __restrict__ idx_p2g,
    const float* __restrict__ pverts, const int* __restrict__ pfaces,
    float* __restrict__ partial) {
  int tid = threadIdx.x;
  int gidx = blockIdx.x * 256 + tid;
  const int stride = kPB * 256;
  int is64 = faces_is64(pfaces);
  float s1 = 0.f, s2 = 0.f, sc = 0.f, se = 0.f;
  for (int i = gidx; i < kB * kNS; i += stride) {
    s1 += min_p2g[i];
    s2 += min_g2p[i];
    int b = i >> 12;
    int m = idx_p2g[i];
    m = m < 0 ? 0 : (m >= kNS ? kNS - 1 : m);
    const float* pn = pred_nrm + (size_t)i * 3;
    const float* gn = gt_nrm + ((size_t)b * kNS + m) * 3;
    sc += fabsf(pn[0]*gn[0] + pn[1]*gn[1] + pn[2]*gn[2]);
  }
  for (int e = gidx; e < kB * kFP * 3; e += stride) {
    int b = e / (kFP * 3);
    int r = e - b * kFP * 3;
    int f = r / 3, k = r - f * 3;
    int ia, ib;
    if (k == 0)      { ia = face_vtx(pfaces, f, 0, is64, kVP); ib = face_vtx(pfaces, f, 1, is64, kVP); }
    else if (k == 1) { ia = face_vtx(pfaces, f, 1, is64, kVP); ib = face_vtx(pfaces, f, 2, is64, kVP); }
    else             { ia = face_vtx(pfaces, f, 2, is64, kVP); ib = face_vtx(pfaces, f, 0, is64, kVP); }
    const float* vb = pverts + (size_t)b * kVP * 3;
    float dx = vb[ib*3+0] - vb[ia*3+0];
    float dy = vb[ib*3+1] - vb[ia*3+1];
    float dz = vb[ib*3+2] - vb[ia*3+2];
    se += dx*dx + dy*dy + dz*dz;
  }
  __shared__ float r1a[256], r2a[256], r3a[256], r4a[256];
  r1a[tid] = s1; r2a[tid] = s2; r3a[tid] = sc; r4a[tid] = se;
  __syncthreads();
  for (int off = 128; off > 0; off >>= 1) {
    if (tid < off) {
      r1a[tid] += r1a[tid+off];
      r2a[tid] += r2a[tid+off];
      r3a[tid] += r3a[tid+off];
      r4a[tid] += r4a[tid+off];
    }
    __syncthreads();
  }
  if (tid == 0) {
    partial[blockIdx.x*4+0] = r1a[0];
    partial[blockIdx.x*4+1] = r2a[0];
    partial[blockIdx.x*4+2] = r3a[0];
    partial[blockIdx.x*4+3] = r4a[0];
  }
}

// ---------------- loss reduction stage 2: combine kPB partials ----------------
__global__ __launch_bounds__(256) void mlk_loss_combine(
    const float* __restrict__ partial, float* __restrict__ out) {
  int tid = threadIdx.x;
  __shared__ float r1a[256], r2a[256], r3a[256], r4a[256];
  r1a[tid] = partial[tid*4+0];
  r2a[tid] = partial[tid*4+1];
  r3a[tid] = partial[tid*4+2];
  r4a[tid] = partial[tid*4+3];
  __syncthreads();
  for (int off = 128; off > 0; off >>= 1) {
    if (tid < off) {
      r1a[tid] += r1a[tid+off];
      r2a[tid] += r2a[tid+off];
      r3a[tid] += r3a[tid+off];
      r4a[tid] += r4a[tid+off];
    }
    __syncthreads();
  }
  if (tid == 0) {
    const float invN = 1.0f / (float)(kB * kNS);
    float chamfer = r1a[0] * invN + r2a[0] * invN;
    float nloss = 1.0f - r3a[0] * invN;
    float eloss = r4a[0] / (float)(kB * kFP * 3);
    out[0] = 1.0f * chamfer + 0.1f * nloss + 0.5f * eloss;
  }
}

// ---------------- host side ----------------
extern "C" void kernel_launch(void* const* d_in, const int* in_sizes, int n_in,
                              void* d_out, int out_size, void* d_ws, size_t ws_size,
                              hipStream_t stream) {
  const float* pverts = (const float*)d_in[0];
  const int*   pfaces = (const int*)d_in[1];
  const float* gverts = (const float*)d_in[2];
  const int*   gfaces = (const int*)d_in[3];
  float* out = (float*)d_out;

  const size_t needF =
      (size_t)kB*kFP + (size_t)kB*kFG +          // weights -> prefix (in-place)
      (size_t)kB*kFP*3 + (size_t)kB*kFG*3 +
      4*(size_t)kB*kNS*3 +
      2*(size_t)kB*kNS +
      (size_t)kPB*4 +
      (size_t)kB*kNS;                            // idx_p2g
  if (ws_size < needF * 4) {
    mlk_write_scalar<<<1, 64, 0, stream>>>(out, -1.0f);
    return;
  }

  // --- JAX threefry key chain (host, pure arithmetic) ---
  uint32_t a0 = 0u, a1 = 2u; tf2x32(0u, 42u, a0, a1);
  uint32_t b0 = 1u, b1 = 3u; tf2x32(0u, 42u, b0, b1);
  uint32_t kp0 = a0, kp1 = b0;
  uint32_t kg0 = a1, kg1 = b1;
  uint32_t kpred[6], kgt[6];
  {
    uint32_t p0 = 0u, p1 = 3u; tf2x32(kp0, kp1, p0, p1);
    uint32_t q0 = 1u, q1 = 4u; tf2x32(kp0, kp1, q0, q1);
    uint32_t r0 = 2u, r1 = 5u; tf2x32(kp0, kp1, r0, r1);
    kpred[0]=p0; kpred[1]=q0; kpred[2]=r0; kpred[3]=p1; kpred[4]=q1; kpred[5]=r1;
  }
  {
    uint32_t p0 = 0u, p1 = 3u; tf2x32(kg0, kg1, p0, p1);
    uint32_t q0 = 1u, q1 = 4u; tf2x32(kg0, kg1, q0, q1);
    uint32_t r0 = 2u, r1 = 5u; tf2x32(kg0, kg1, r0, r1);
    kgt[0]=p0; kgt[1]=q0; kgt[2]=r0; kgt[3]=p1; kgt[4]=q1; kgt[5]=r1;
  }

  // --- workspace carve (all 4-byte elements) ---
  float* ws = (float*)d_ws;
  float* pref_p   = ws; ws += kB * kFP;          // weights, then in-place prefix
  float* pref_g   = ws; ws += kB * kFG;
  float* fnrm_p   = ws; ws += kB * kFP * 3;
  float* fnrm_g   = ws; ws += kB * kFG * 3;
  float* pred_pts = ws; ws += kB * kNS * 3;
  float* gt_pts   = ws; ws += kB * kNS * 3;
  float* pred_nrm = ws; ws += kB * kNS * 3;
  float* gt_nrm   = ws; ws += kB * kNS * 3;
  float* min_p2g  = ws; ws += kB * kNS;
  float* min_g2p  = ws; ws += kB * kNS;
  float* partial  = ws; ws += kPB * 4;
  int* idx_p2g = (int*)ws; ws += kB * kNS;

  mlk_prep_faces2<<<kPREP_P + kPREP_G, 256, 0, stream>>>(
      pverts, pfaces, gverts, gfaces, pref_p, fnrm_p, pref_g, fnrm_g);

  mlk_prefix2<<<8, 256, 0, stream>>>(pref_p, pref_g);

  mlk_sample_gen<<<64, 256, 0, stream>>>(
      pverts, pfaces, pref_p, fnrm_p, pred_pts, pred_nrm,
      gverts, gfaces, pref_g, fnrm_g, gt_pts, gt_nrm,
      kpred[0], kpred[1], kpred[2], kpred[3], kpred[4], kpred[5],
      kgt[0],  kgt[1],  kgt[2],  kgt[3],  kgt[4],  kgt[5]);

  mlk_chamfer4<<<512, 512, 0, stream>>>(pred_pts, gt_pts, min_p2g, min_g2p, idx_p2g);

  mlk_loss_partial<<<kPB, 256, 0, stream>>>(min_p2g, min_g2p, pred_nrm, gt_nrm, idx_p2g,
                                            pverts, pfaces, partial);
  mlk_loss_combine<<<1, 256, 0, stream>>>(partial, out);
}

// Round 10
// 70.392 us; speedup vs baseline: 1.4250x; 1.2057x over previous
//
#include <hip/hip_runtime.h>
#include <stdint.h>

constexpr int   kB  = 4;
constexpr int   kNS = 4096;
constexpr int   kVP = 2562;
constexpr int   kFP = 5120;
constexpr int   kVG = 6890;
constexpr int   kFG = 13776;
constexpr float kEPS  = 1e-12f;
constexpr int   kPB  = 256;   // partial-reduction blocks
constexpr int   kPREP_P = (kB * kFP + 255) / 256;   // 80
constexpr int   kPREP_G = (kB * kFG + 255) / 256;   // 216
constexpr int   kHN = kB * kNS;                     // 16384 (per ref-half arrays)

// ---------------- Threefry-2x32 (exact JAX semantics) ----------------
__host__ __device__ inline void tf2x32(uint32_t k0, uint32_t k1,
                                       uint32_t& x0r, uint32_t& x1r) {
  uint32_t ks2 = k0 ^ k1 ^ 0x1BD11BDAu;
  uint32_t x0 = x0r + k0, x1 = x1r + k1;
#define TF_R(r) { x0 += x1; x1 = (x1 << (r)) | (x1 >> (32 - (r))); x1 ^= x0; }
  TF_R(13) TF_R(15) TF_R(26) TF_R(6)
  x0 += k1;  x1 += ks2 + 1u;
  TF_R(17) TF_R(29) TF_R(16) TF_R(24)
  x0 += ks2; x1 += k0 + 2u;
  TF_R(13) TF_R(15) TF_R(26) TF_R(6)
  x0 += k0;  x1 += k1 + 3u;
  TF_R(17) TF_R(29) TF_R(16) TF_R(24)
  x0 += k1;  x1 += ks2 + 4u;
  TF_R(13) TF_R(15) TF_R(26) TF_R(6)
  x0 += ks2; x1 += k0 + 5u;
#undef TF_R
  x0r = x0; x1r = x1;
}

__device__ inline float bits_to_unit(uint32_t b) {
  // JAX: bitcast((b>>9)|0x3f800000) - 1.0  ->  [0,1)
  return __uint_as_float((b >> 9) | 0x3f800000u) - 1.0f;
}

// faces may arrive as int32 (documented) or int64 (reference dtype). For
// int64 little-endian with values < 2^31, every odd 32-bit word is 0.
__device__ inline int faces_is64(const int* __restrict__ faces) {
  return (faces[1] == 0 && faces[3] == 0 && faces[5] == 0 && faces[7] == 0) ? 1 : 0;
}
__device__ inline int face_vtx(const int* __restrict__ faces, int f, int c,
                               int is64, int V) {
  int e = f * 3 + c;
  int v = faces[is64 ? (e << 1) : e];
  return v < 0 ? 0 : (v >= V ? V - 1 : v);
}

// ---------------- trivial diagnostic kernel ----------------
__global__ void mlk_write_scalar(float* out, float val) {
  if (threadIdx.x == 0 && blockIdx.x == 0) out[0] = val;
}

// ---------------- fused face geometry for BOTH meshes ----------------
__global__ __launch_bounds__(256) void mlk_prep_faces2(
    const float* __restrict__ pverts, const int* __restrict__ pfaces,
    const float* __restrict__ gverts, const int* __restrict__ gfaces,
    float* __restrict__ wp, float* __restrict__ np,
    float* __restrict__ wg, float* __restrict__ ng) {
  int which = blockIdx.x >= kPREP_P;
  int blk   = which ? blockIdx.x - kPREP_P : blockIdx.x;
  const float* verts = which ? gverts : pverts;
  const int*   faces = which ? gfaces : pfaces;
  float* warea = which ? wg : wp;
  float* fnrm  = which ? ng : np;
  int V = which ? kVG : kVP;
  int F = which ? kFG : kFP;
  int idx = blk * 256 + threadIdx.x;
  if (idx >= kB * F) return;
  int is64 = faces_is64(faces);
  int b = idx / F, f = idx - b * F;
  int i0 = face_vtx(faces, f, 0, is64, V);
  int i1 = face_vtx(faces, f, 1, is64, V);
  int i2 = face_vtx(faces, f, 2, is64, V);
  const float* vb = verts + (size_t)b * V * 3;
  float ax = vb[i0*3+0], ay = vb[i0*3+1], az = vb[i0*3+2];
  float bx = vb[i1*3+0], by = vb[i1*3+1], bz = vb[i1*3+2];
  float cx = vb[i2*3+0], cy = vb[i2*3+1], cz = vb[i2*3+2];
  float e1x = bx-ax, e1y = by-ay, e1z = bz-az;
  float e2x = cx-ax, e2y = cy-ay, e2z = cz-az;
  float nx = e1y*e2z - e1z*e2y;
  float ny = e1z*e2x - e1x*e2z;
  float nz = e1x*e2y - e1y*e2x;
  float area2 = sqrtf(nx*nx + ny*ny + nz*nz);   // 2*area
  warea[idx] = 0.5f * area2 + kEPS;             // categorical weight
  float inv_n = 1.0f / (area2 + kEPS);
  fnrm[3*idx+0] = nx*inv_n;
  fnrm[3*idx+1] = ny*inv_n;
  fnrm[3*idx+2] = nz*inv_n;
}

// ---------------- fused in-place prefix sums (8 blocks x 1024 thr) -----------
__global__ __launch_bounds__(1024) void mlk_prefix2(
    float* __restrict__ wp, float* __restrict__ wg) {
  int which = blockIdx.x >> 2;
  int b = blockIdx.x & 3, tid = threadIdx.x;
  int F = which ? kFG : kFP;
  float* wb = (which ? wg : wp) + (size_t)b * F;
  int C = (F + 1023) / 1024;        // 5 (pred) / 14 (gt)
  int lo = tid * C;
  int hi = lo + C; if (hi > F) hi = F; if (lo > F) lo = F;
  float s = 0.f;
  for (int i = lo; i < hi; ++i) s += wb[i];
  __shared__ float ps[1024];
  ps[tid] = s;
  __syncthreads();
  for (int off = 1; off < 1024; off <<= 1) {
    float v = (tid >= off) ? ps[tid - off] : 0.f;
    __syncthreads();
    ps[tid] += v;
    __syncthreads();
  }
  float p = ps[tid] - s;            // exclusive offset for this chunk
  for (int i = lo; i < hi; ++i) { p += wb[i]; wb[i] = p; }
}

// ---------------- fused categorical (inverse-CDF) + barycentric gen ----------
// grid 64: blocks 0..31 pred, 32..63 gt. Thread t handles rows t and t+8192.
__global__ __launch_bounds__(256) void mlk_sample_gen(
    const float* __restrict__ pverts, const int* __restrict__ pfaces,
    const float* __restrict__ pref_p, const float* __restrict__ fnrm_p,
    float* __restrict__ pred_pts, float* __restrict__ pred_nrm,
    const float* __restrict__ gverts, const int* __restrict__ gfaces,
    const float* __restrict__ pref_g, const float* __restrict__ fnrm_g,
    float* __restrict__ gt_pts, float* __restrict__ gt_nrm,
    uint32_t pf0, uint32_t pf1, uint32_t pu0, uint32_t pu1, uint32_t pv0, uint32_t pv1,
    uint32_t gf0, uint32_t gf1, uint32_t gu0, uint32_t gu1, uint32_t gv0, uint32_t gv1) {
  int which = blockIdx.x >> 5;
  int t = ((blockIdx.x & 31) << 8) + threadIdx.x;   // 0..8191
  const float* verts = which ? gverts : pverts;
  const int*   faces = which ? gfaces : pfaces;
  const float* pref  = which ? pref_g : pref_p;
  const float* fnrm  = which ? fnrm_g : fnrm_p;
  float* pts  = which ? gt_pts : pred_pts;
  float* pnrm = which ? gt_nrm : pred_nrm;
  int V = which ? kVG : kVP;
  int F = which ? kFG : kFP;
  uint32_t kf0 = which ? gf0 : pf0, kf1 = which ? gf1 : pf1;
  uint32_t ku0 = which ? gu0 : pu0, ku1 = which ? gu1 : pu1;
  uint32_t kv0 = which ? gv0 : pv0, kv1 = which ? gv1 : pv1;
  int is64 = faces_is64(faces);

  uint32_t fx0 = (uint32_t)t, fx1 = (uint32_t)(t + 8192);
  tf2x32(kf0, kf1, fx0, fx1);
  uint32_t ux0 = (uint32_t)t, ux1 = (uint32_t)(t + 8192);
  tf2x32(ku0, ku1, ux0, ux1);
  uint32_t vx0 = (uint32_t)t, vx1 = (uint32_t)(t + 8192);
  tf2x32(kv0, kv1, vx0, vx1);

#pragma unroll
  for (int half = 0; half < 2; ++half) {
    int i = t + half * 8192;                    // flat (b*kNS+s)
    int b = i >> 12;
    // --- inverse-CDF face draw ---
    float uf = bits_to_unit(half ? fx1 : fx0);
    const float* Pb = pref + (size_t)b * F;
    float target = uf * Pb[F - 1];
    int lo = 0, hi = F - 1;
    while (lo < hi) {                           // first f with P_incl[f] > target
      int mid = (lo + hi) >> 1;
      if (Pb[mid] > target) hi = mid; else lo = mid + 1;
    }
    int fid = lo;
    // --- barycentric point ---
    float u = bits_to_unit(half ? ux1 : ux0);
    float v = bits_to_unit(half ? vx1 : vx0);
    const float* vb = verts + (size_t)b * V * 3;
    int i0 = face_vtx(faces, fid, 0, is64, V);
    int i1 = face_vtx(faces, fid, 1, is64, V);
    int i2 = face_vtx(faces, fid, 2, is64, V);
    float r1 = sqrtf(u);
    float w0 = 1.0f - r1, w1 = r1 * (1.0f - v), w2 = r1 * v;
#pragma unroll
    for (int c = 0; c < 3; ++c) {
      pts[i*3+c] = w0 * vb[i0*3+c] + w1 * vb[i1*3+c] + w2 * vb[i2*3+c];
      pnrm[i*3+c] = fnrm[((size_t)b*F + fid)*3 + c];
    }
  }
}

// ---------------- chamfer v5: ref-halved, 2 queries/lane ---------------------
// grid = 512: dir(2) x batch(4) x qc(32) x refhalf(2). Block = 256 thr = 4 waves.
// Block stages 2048 refs (its half) in 24KB SoA LDS; serves 128 queries
// (2/lane: q0 = qc*128+lane, q1 = q0+64). Wave w scans local refs
// [512w, 512w+512) as 128 float4 groups -> each broadcast ds_read_b128 feeds
// 128 evals. Min chains split A{0,1}/B{2,3}; merges tie-break to smaller index.
// Halves merged later in mlk_loss_partial (half0 wins ties; all half0 indices
// < half1 indices => exact first-index argmin preserved).
__global__ __launch_bounds__(256) void mlk_chamfer5(
    const float* __restrict__ pred_pts, const float* __restrict__ gt_pts,
    float* __restrict__ minh_p2g, float* __restrict__ minh_g2p,
    int* __restrict__ idxh_p2g) {
  int bid = blockIdx.x;
  int dir = bid >> 8;            // 0: pred->gt (needs idx), 1: gt->pred
  int r   = bid & 255;
  int b   = r >> 6;
  int rr  = r & 63;
  int qc  = rr >> 1;             // 0..31
  int rh  = rr & 1;              // ref half
  const float* qpts = dir ? gt_pts   : pred_pts;
  const float* rpts = dir ? pred_pts : gt_pts;
  int wave = threadIdx.x >> 6;
  int lane = threadIdx.x & 63;

  constexpr int HR = kNS / 2;    // 2048 refs per half
  __shared__ float4 lpx4[HR/4], lpy4[HR/4], lpz4[HR/4];  // 24 KB SoA
  float* lpx = (float*)lpx4; float* lpy = (float*)lpy4; float* lpz = (float*)lpz4;
  const float* rb = rpts + (size_t)b * kNS * 3 + (size_t)rh * HR * 3;
  for (int i = threadIdx.x; i < HR; i += 256) {
    lpx[i] = rb[3*i+0];
    lpy[i] = rb[3*i+1];
    lpz[i] = rb[3*i+2];
  }
  __syncthreads();

  int q0 = qc * 128 + lane;           // query pair q0, q0+64
  int gq0 = b * kNS + q0;
  int gq1 = gq0 + 64;
  float px0 = qpts[gq0*3+0], py0 = qpts[gq0*3+1], pz0 = qpts[gq0*3+2];
  float px1 = qpts[gq1*3+0], py1 = qpts[gq1*3+1], pz1 = qpts[gq1*3+2];
  int j0 = wave * 128;                // 128 float4 groups = 512 refs / wave
  float best0, best1; int bidx0 = 0, bidx1 = 0;

  if (dir == 0) {
    float bA0 = INFINITY, bB0 = INFINITY, bA1 = INFINITY, bB1 = INFINITY;
    int iA0 = 0, iB0 = 0, iA1 = 0, iB1 = 0;
#pragma unroll 2
    for (int j = j0; j < j0 + 128; ++j) {
      float4 X = lpx4[j], Y = lpy4[j], Z = lpz4[j];
      int m = j << 2;
      float dx, dy, dz, d;
      dx = px0-X.x; dy = py0-Y.x; dz = pz0-Z.x; d = dx*dx+dy*dy+dz*dz; if (d < bA0) { bA0 = d; iA0 = m; }
      dx = px0-X.y; dy = py0-Y.y; dz = pz0-Z.y; d = dx*dx+dy*dy+dz*dz; if (d < bA0) { bA0 = d; iA0 = m|1; }
      dx = px0-X.z; dy = py0-Y.z; dz = pz0-Z.z; d = dx*dx+dy*dy+dz*dz; if (d < bB0) { bB0 = d; iB0 = m|2; }
      dx = px0-X.w; dy = py0-Y.w; dz = pz0-Z.w; d = dx*dx+dy*dy+dz*dz; if (d < bB0) { bB0 = d; iB0 = m|3; }
      dx = px1-X.x; dy = py1-Y.x; dz = pz1-Z.x; d = dx*dx+dy*dy+dz*dz; if (d < bA1) { bA1 = d; iA1 = m; }
      dx = px1-X.y; dy = py1-Y.y; dz = pz1-Z.y; d = dx*dx+dy*dy+dz*dz; if (d < bA1) { bA1 = d; iA1 = m|1; }
      dx = px1-X.z; dy = py1-Y.z; dz = pz1-Z.z; d = dx*dx+dy*dy+dz*dz; if (d < bB1) { bB1 = d; iB1 = m|2; }
      dx = px1-X.w; dy = py1-Y.w; dz = pz1-Z.w; d = dx*dx+dy*dy+dz*dz; if (d < bB1) { bB1 = d; iB1 = m|3; }
    }
    if (bB0 < bA0 || (bB0 == bA0 && iB0 < iA0)) { best0 = bB0; bidx0 = iB0; } else { best0 = bA0; bidx0 = iA0; }
    if (bB1 < bA1 || (bB1 == bA1 && iB1 < iA1)) { best1 = bB1; bidx1 = iB1; } else { best1 = bA1; bidx1 = iA1; }
  } else {
    float bA0 = INFINITY, bB0 = INFINITY, bA1 = INFINITY, bB1 = INFINITY;
#pragma unroll 2
    for (int j = j0; j < j0 + 128; ++j) {
      float4 X = lpx4[j], Y = lpy4[j], Z = lpz4[j];
      float dx, dy, dz;
      dx = px0-X.x; dy = py0-Y.x; dz = pz0-Z.x; float d0 = dx*dx+dy*dy+dz*dz;
      dx = px0-X.y; dy = py0-Y.y; dz = pz0-Z.y; float d1 = dx*dx+dy*dy+dz*dz;
      dx = px0-X.z; dy = py0-Y.z; dz = pz0-Z.z; float d2 = dx*dx+dy*dy+dz*dz;
      dx = px0-X.w; dy = py0-Y.w; dz = pz0-Z.w; float d3 = dx*dx+dy*dy+dz*dz;
      bA0 = fminf(bA0, fminf(d0, d1));
      bB0 = fminf(bB0, fminf(d2, d3));
      dx = px1-X.x; dy = py1-Y.x; dz = pz1-Z.x; d0 = dx*dx+dy*dy+dz*dz;
      dx = px1-X.y; dy = py1-Y.y; dz = pz1-Z.y; d1 = dx*dx+dy*dy+dz*dz;
      dx = px1-X.z; dy = py1-Y.z; dz = pz1-Z.z; d2 = dx*dx+dy*dy+dz*dz;
      dx = px1-X.w; dy = py1-Y.w; dz = pz1-Z.w; d3 = dx*dx+dy*dy+dz*dz;
      bA1 = fminf(bA1, fminf(d0, d1));
      bB1 = fminf(bB1, fminf(d2, d3));
    }
    best0 = fminf(bA0, bB0);
    best1 = fminf(bA1, bB1);
  }

  __shared__ float cv[4][128];
  __shared__ int   ci[4][128];
  cv[wave][lane]      = best0; ci[wave][lane]      = bidx0;
  cv[wave][lane + 64] = best1; ci[wave][lane + 64] = bidx1;
  __syncthreads();
  if (threadIdx.x < 128) {
    int ql = threadIdx.x;
    float bv = cv[0][ql]; int bi = ci[0][ql];
#pragma unroll
    for (int wv = 1; wv < 4; ++wv) {
      float v = cv[wv][ql];
      int   i = ci[wv][ql];
      if (v < bv || (v == bv && i < bi)) { bv = v; bi = i; }
    }
    int gi = rh * kHN + b * kNS + qc * 128 + ql;   // [half][flat]
    if (dir == 0) { minh_p2g[gi] = bv; idxh_p2g[gi] = rh * HR + bi; }
    else          { minh_g2p[gi] = bv; }
  }
}

// ---------------- loss reduction stage 1: grid-wide partials -----------------
// Merges the two chamfer ref-halves (strict <: half0 wins ties = smaller idx).
__global__ __launch_bounds__(256) void mlk_loss_partial(
    const float* __restrict__ minh_p2g, const float* __restrict__ minh_g2p,
    const float* __restrict__ pred_nrm, const float* __restrict__ gt_nrm,
    const int* __restrict__ idxh_p2g,
    const float* __restrict__ pverts, const int* __restrict__ pfaces,
    float* __restrict__ partial) {
  int tid = threadIdx.x;
  int gidx = blockIdx.x * 256 + tid;
  const int stride = kPB * 256;
  int is64 = faces_is64(pfaces);
  float s1 = 0.f, s2 = 0.f, sc = 0.f, se = 0.f;
  for (int i = gidx; i < kHN; i += stride) {
    float v0 = minh_p2g[i], v1 = minh_p2g[kHN + i];
    int   j0 = idxh_p2g[i], j1 = idxh_p2g[kHN + i];
    float mv; int m;
    if (v1 < v0) { mv = v1; m = j1; } else { mv = v0; m = j0; }
    s1 += mv;
    s2 += fminf(minh_g2p[i], minh_g2p[kHN + i]);
    int b = i >> 12;
    m = m < 0 ? 0 : (m >= kNS ? kNS - 1 : m);
    const float* pn = pred_nrm + (size_t)i * 3;
    const float* gn = gt_nrm + ((size_t)b * kNS + m) * 3;
    sc += fabsf(pn[0]*gn[0] + pn[1]*gn[1] + pn[2]*gn[2]);
  }
  for (int e = gidx; e < kB * kFP * 3; e += stride) {
    int b = e / (kFP * 3);
    int r = e - b * kFP * 3;
    int f = r / 3, k = r - f * 3;
    int ia, ib;
    if (k == 0)      { ia = face_vtx(pfaces, f, 0, is64, kVP); ib = face_vtx(pfaces, f, 1, is64, kVP); }
    else if (k == 1) { ia = face_vtx(pfaces, f, 1, is64, kVP); ib = face_vtx(pfaces, f, 2, is64, kVP); }
    else             { ia = face_vtx(pfaces, f, 2, is64, kVP); ib = face_vtx(pfaces, f, 0, is64, kVP); }
    const float* vb = pverts + (size_t)b * kVP * 3;
    float dx = vb[ib*3+0] - vb[ia*3+0];
    float dy = vb[ib*3+1] - vb[ia*3+1];
    float dz = vb[ib*3+2] - vb[ia*3+2];
    se += dx*dx + dy*dy + dz*dz;
  }
  __shared__ float r1a[256], r2a[256], r3a[256], r4a[256];
  r1a[tid] = s1; r2a[tid] = s2; r3a[tid] = sc; r4a[tid] = se;
  __syncthreads();
  for (int off = 128; off > 0; off >>= 1) {
    if (tid < off) {
      r1a[tid] += r1a[tid+off];
      r2a[tid] += r2a[tid+off];
      r3a[tid] += r3a[tid+off];
      r4a[tid] += r4a[tid+off];
    }
    __syncthreads();
  }
  if (tid == 0) {
    partial[blockIdx.x*4+0] = r1a[0];
    partial[blockIdx.x*4+1] = r2a[0];
    partial[blockIdx.x*4+2] = r3a[0];
    partial[blockIdx.x*4+3] = r4a[0];
  }
}

// ---------------- loss reduction stage 2: combine kPB partials ----------------
__global__ __launch_bounds__(256) void mlk_loss_combine(
    const float* __restrict__ partial, float* __restrict__ out) {
  int tid = threadIdx.x;
  __shared__ float r1a[256], r2a[256], r3a[256], r4a[256];
  r1a[tid] = partial[tid*4+0];
  r2a[tid] = partial[tid*4+1];
  r3a[tid] = partial[tid*4+2];
  r4a[tid] = partial[tid*4+3];
  __syncthreads();
  for (int off = 128; off > 0; off >>= 1) {
    if (tid < off) {
      r1a[tid] += r1a[tid+off];
      r2a[tid] += r2a[tid+off];
      r3a[tid] += r3a[tid+off];
      r4a[tid] += r4a[tid+off];
    }
    __syncthreads();
  }
  if (tid == 0) {
    const float invN = 1.0f / (float)(kB * kNS);
    float chamfer = r1a[0] * invN + r2a[0] * invN;
    float nloss = 1.0f - r3a[0] * invN;
    float eloss = r4a[0] / (float)(kB * kFP * 3);
    out[0] = 1.0f * chamfer + 0.1f * nloss + 0.5f * eloss;
  }
}

// ---------------- host side ----------------
extern "C" void kernel_launch(void* const* d_in, const int* in_sizes, int n_in,
                              void* d_out, int out_size, void* d_ws, size_t ws_size,
                              hipStream_t stream) {
  const float* pverts = (const float*)d_in[0];
  const int*   pfaces = (const int*)d_in[1];
  const float* gverts = (const float*)d_in[2];
  const int*   gfaces = (const int*)d_in[3];
  float* out = (float*)d_out;

  const size_t needF =
      (size_t)kB*kFP + (size_t)kB*kFG +          // weights -> prefix (in-place)
      (size_t)kB*kFP*3 + (size_t)kB*kFG*3 +
      4*(size_t)kB*kNS*3 +
      4*(size_t)kHN +                            // minh p2g/g2p (2 halves each)
      (size_t)kPB*4 +
      2*(size_t)kHN;                             // idxh_p2g (2 halves)
  if (ws_size < needF * 4) {
    mlk_write_scalar<<<1, 64, 0, stream>>>(out, -1.0f);
    return;
  }

  // --- JAX threefry key chain (host, pure arithmetic) ---
  uint32_t a0 = 0u, a1 = 2u; tf2x32(0u, 42u, a0, a1);
  uint32_t b0 = 1u, b1 = 3u; tf2x32(0u, 42u, b0, b1);
  uint32_t kp0 = a0, kp1 = b0;
  uint32_t kg0 = a1, kg1 = b1;
  uint32_t kpred[6], kgt[6];
  {
    uint32_t p0 = 0u, p1 = 3u; tf2x32(kp0, kp1, p0, p1);
    uint32_t q0 = 1u, q1 = 4u; tf2x32(kp0, kp1, q0, q1);
    uint32_t r0 = 2u, r1 = 5u; tf2x32(kp0, kp1, r0, r1);
    kpred[0]=p0; kpred[1]=q0; kpred[2]=r0; kpred[3]=p1; kpred[4]=q1; kpred[5]=r1;
  }
  {
    uint32_t p0 = 0u, p1 = 3u; tf2x32(kg0, kg1, p0, p1);
    uint32_t q0 = 1u, q1 = 4u; tf2x32(kg0, kg1, q0, q1);
    uint32_t r0 = 2u, r1 = 5u; tf2x32(kg0, kg1, r0, r1);
    kgt[0]=p0; kgt[1]=q0; kgt[2]=r0; kgt[3]=p1; kgt[4]=q1; kgt[5]=r1;
  }

  // --- workspace carve (all 4-byte elements) ---
  float* ws = (float*)d_ws;
  float* pref_p   = ws; ws += kB * kFP;          // weights, then in-place prefix
  float* pref_g   = ws; ws += kB * kFG;
  float* fnrm_p   = ws; ws += kB * kFP * 3;
  float* fnrm_g   = ws; ws += kB * kFG * 3;
  float* pred_pts = ws; ws += kB * kNS * 3;
  float* gt_pts   = ws; ws += kB * kNS * 3;
  float* pred_nrm = ws; ws += kB * kNS * 3;
  float* gt_nrm   = ws; ws += kB * kNS * 3;
  float* minh_p2g = ws; ws += 2 * kHN;
  float* minh_g2p = ws; ws += 2 * kHN;
  float* partial  = ws; ws += kPB * 4;
  int* idxh_p2g = (int*)ws; ws += 2 * kHN;

  mlk_prep_faces2<<<kPREP_P + kPREP_G, 256, 0, stream>>>(
      pverts, pfaces, gverts, gfaces, pref_p, fnrm_p, pref_g, fnrm_g);

  mlk_prefix2<<<8, 1024, 0, stream>>>(pref_p, pref_g);

  mlk_sample_gen<<<64, 256, 0, stream>>>(
      pverts, pfaces, pref_p, fnrm_p, pred_pts, pred_nrm,
      gverts, gfaces, pref_g, fnrm_g, gt_pts, gt_nrm,
      kpred[0], kpred[1], kpred[2], kpred[3], kpred[4], kpred[5],
      kgt[0],  kgt[1],  kgt[2],  kgt[3],  kgt[4],  kgt[5]);

  mlk_chamfer5<<<512, 256, 0, stream>>>(pred_pts, gt_pts, minh_p2g, minh_g2p, idxh_p2g);

  mlk_loss_partial<<<kPB, 256, 0, stream>>>(minh_p2g, minh_g2p, pred_nrm, gt_nrm,
                                            idxh_p2g, pverts, pfaces, partial);
  mlk_loss_combine<<<1, 256, 0, stream>>>(partial, out);
}